// Round 14
// baseline (116.960 us; speedup 1.0000x reference)
//
#include <hip/hip_runtime.h>
#include <stdint.h>

#define NB 16
#define NC 256
#define NH 48
#define NW 64
#define ND 21
#define HW (NH * NW)
#define ROW_ELEMS (NW * NC)   // one (b,y) row: 16384 bf16 = 32KB
#define NXCD 8
#define NWG (NB * NH)         // 768 (convert grid)
#define SO_LD 65              // padded plane leading dim (scatter <=4-way)
#define SO_SZ (ND * SO_LD)    // 1365 floats per plane

typedef __bf16 bf16x8 __attribute__((ext_vector_type(8)));
typedef float f32x4 __attribute__((ext_vector_type(4)));

// convert grid (768): XCD k owns wg [k*96, k*96+96) = batches {2k,2k+1}
__device__ __forceinline__ int xcd_wg(int orig) {
    return (orig & (NXCD - 1)) * (NWG / NXCD) + (orig >> 3);
}

// full-row LDS layout [pos][c] bf16, XOR-swizzled 16B chunks (conflict-free b128)
__device__ __forceinline__ int sw_addr(int x, int chunk) {
    int cs = (chunk & ~7) | ((chunk ^ x) & 7);
    return x * 256 + (cs << 3);
}
// parity permutation: even x -> pos 0..31, odd x -> pos 32..63
__device__ __forceinline__ int posx(int x) { return ((x & 1) << 5) | (x >> 1); }

// ws (in2) GLOBAL fragment order: slice w=(nt<<1)|par, per-kb 1KB contiguous
__device__ __forceinline__ int frag_off(int w, int kb, int l) {
    return w * 4096 + kb * 512 + ((l ^ ((w & 3) << 1)) << 3);
}

__device__ __forceinline__ bf16x8 load_pack8(const float* __restrict__ p, int cbase) {
    bf16x8 v;
#pragma unroll
    for (int j = 0; j < 8; ++j)
        v[j] = (__bf16)p[(size_t)(cbase + j) * HW];
    return v;
}

// ---------- pre-pass: in2 fp32 [b][c][h][w] -> ws bf16 rows (fragment order) --
__global__ void __launch_bounds__(256, 4)
convert_in2(const float* __restrict__ in2, unsigned short* __restrict__ ws) {
    __shared__ unsigned short s[ROW_ELEMS];
    const int tid = threadIdx.x;
    const int wg = xcd_wg(blockIdx.x);
    const int b = wg / NH, y = wg % NH;
    const int x = tid & 63, g0 = tid >> 6;
    const int par = x & 1, m_lo = (x >> 1) & 15, nt = x >> 5;
    const int w = (nt << 1) | par;
    const float* p = in2 + ((size_t)b * NC * NH + y) * NW + x;
#pragma unroll
    for (int i = 0; i < 8; ++i) {
        const int chunk = g0 * 8 + i;
        const int kb = chunk >> 2, quad = chunk & 3;
        const int l = (quad << 4) | m_lo;
        bf16x8 v = load_pack8(p, chunk * 8);
        *(bf16x8*)&s[frag_off(w, kb, l)] = v;
    }
    __syncthreads();
    unsigned short* wr = ws + ((size_t)b * NH + y) * ROW_ELEMS;
#pragma unroll
    for (int i = 0; i < 8; ++i) {
        const int e = (i * 256 + tid) * 8;
        *(bf16x8*)(wr + e) = *(const bf16x8*)(s + e);
    }
}

// ---------- main: block = (b, P, 4-y group, ys-third); 576 blocks x 512 -----
// Small enough (54.6KB LDS, <=128 VGPR at 4 waves/SIMD) that TWO independent
// blocks co-reside per CU: whole-block barrier/latency stalls finally overlap.
// Step keeps the proven pieces: Bst reg-prefetch -> single bbuf, fragment ws
// layout, padded single-set planes with same-step drain, raw lgkm barriers.
__global__ void __launch_bounds__(512, 4)
corr_main(const float* __restrict__ in1, const unsigned short* __restrict__ ws,
          float* __restrict__ out) {
    // [0,32768): bbuf (B row; also prologue in1 staging)
    // [32768,54608): 4 sout planes [ND][SO_LD]
    __shared__ __align__(16) unsigned char smem[54608];
    unsigned short* bbuf  = (unsigned short*)smem;
    float*          soutf = (float*)(smem + 32768);

    const int tid = threadIdx.x;
    const int bid = blockIdx.x;
    const int xcd = bid & 7;                  // all blocks of b on one XCD
    const int r   = bid >> 3;                 // 0..71
    const int b   = 2 * xcd + (r >= 36 ? 1 : 0);
    const int v   = r - (r >= 36 ? 36 : 0);   // 0..35
    const int P   = v & 1;
    const int w2  = v >> 1;                   // 0..17
    const int g   = w2 % 6, ti = w2 / 6;      // y-group, ys-third
    const int y0  = 8 * g + P;

    const int lane = tid & 63, wave = tid >> 6;   // 8 waves
    const int m_lo = lane & 15, quad = lane >> 4;
    const int par  = wave & 1, yy = wave >> 1;    // wave = (par, yy in 0..3)
    const int y    = y0 + 2 * yy;                 // this wave's output row

    const int lo = max(y0 - 20, P);
    const int hi = min(y0 + 26, 46 + P);
    const int n  = ((hi - lo) >> 1) + 1;          // 14..22
    const int q  = (n + 2) / 3;                   // 5..8
    const int lo_t = lo + 2 * q * ti;
    const int nh   = min(q, n - q * ti);          // >= 4 always

    const unsigned short* wsb = ws + (size_t)b * NH * ROW_ELEMS;

    // early prefetch of the first B row into regs (hides under in1 prologue)
    bf16x8 Bst[4];
    {
        const unsigned short* row = wsb + (size_t)lo_t * ROW_ELEMS;
#pragma unroll
        for (int k2 = 0; k2 < 4; ++k2)
            Bst[k2] = *(const bf16x8*)&row[(tid + 512 * k2) * 8];
    }

    // ---- prologue: 4 rounds; stage in1 row y0+2*rnd into bbuf; wave-pair
    // yy==rnd extracts its A fragments (A stays in registers all kernel)
    bf16x8 afrag[2][8];
#pragma unroll 1
    for (int rnd = 0; rnd < 4; ++rnd) {
        const float* pr = in1 + ((size_t)b * NC * NH + (y0 + 2 * rnd)) * NW;
#pragma unroll
        for (int i = 0; i < 4; ++i) {
            const int pk = i * 512 + tid;          // 2048 packs per row
            const int x = pk & 63, ch = pk >> 6;
            bf16x8 vv = load_pack8(pr + x, ch * 8);
            *(bf16x8*)&bbuf[sw_addr(posx(x), ch)] = vv;
        }
        __asm__ __volatile__("s_waitcnt lgkmcnt(0)\n\ts_barrier" ::: "memory");
        if (yy == rnd) {
            const int pos0 = par * 32 + m_lo;
#pragma unroll
            for (int kb = 0; kb < 8; ++kb) {
                afrag[0][kb] = *(const bf16x8*)&bbuf[sw_addr(pos0,      4 * kb + quad)];
                afrag[1][kb] = *(const bf16x8*)&bbuf[sw_addr(pos0 + 16, 4 * kb + quad)];
            }
        }
        __asm__ __volatile__("s_waitcnt lgkmcnt(0)\n\ts_barrier" ::: "memory");
    }

    // first B row -> bbuf; zero the 4 planes (band-invalid slots stay zero)
#pragma unroll
    for (int k2 = 0; k2 < 4; ++k2)
        *(bf16x8*)&bbuf[(tid + 512 * k2) * 8] = Bst[k2];
    for (int i = tid; i < 4 * SO_SZ; i += 512) soutf[i] = 0.0f;

    // zero out-of-range dy planes (only the ti==0 block of each group)
    float* outyy = out + (size_t)b * (ND * ND) * HW + (size_t)y * NW;
    const int d0 = (y >= 20) ? 0 : ((21 - y) >> 1);
    const int d1 = min(20, (67 - y) >> 1);
    const int t2 = par * 64 + lane;               // 0..127 in wave-pair
    if (ti == 0) {
        for (int z = 0; z < ND; ++z) {
            if (z >= d0 && z <= d1) continue;
            float* ob = outyy + (size_t)z * ND * HW;
#pragma unroll
            for (int i = 0; i < 11; ++i) {
                const int e = i * 128 + t2;
                if (e < ND * NW)
                    __builtin_nontemporal_store(0.0f, &ob[(size_t)(e >> 6) * HW + (e & 63)]);
            }
        }
    }
    __asm__ __volatile__("s_waitcnt lgkmcnt(0)\n\ts_barrier" ::: "memory");

    const float scale = 1.0f / 256.0f;
    const int boff0 = frag_off((0 << 1) | par, 0, lane);
    const int boff1 = frag_off((1 << 1) | par, 0, lane);
    const int D0 = ((lo_t - y) >> 1) + 10;        // dyi at k=0

    // step (2 phases):
    //  A: prefetch row k+1 -> Bst regs; 32 MFMA from bbuf; scatter plane yy.
    //     bar(lgkm) — scatter visible.
    //  B: write Bst -> bbuf (waits only its own loads); drain plane yy ->
    //     global nt (fire-and-forget). bar(lgkm) — bbuf + plane reads done.
    for (int k = 0; k < nh; ++k) {
        const int dyi = D0 + k;
        const bool valid = (unsigned)dyi <= 20u;   // wave-uniform
        const bool more = (k + 1 < nh);

        if (more) {
            const unsigned short* row = wsb + (size_t)(lo_t + 2 * (k + 1)) * ROW_ELEMS;
#pragma unroll
            for (int k2 = 0; k2 < 4; ++k2)
                Bst[k2] = *(const bf16x8*)&row[(tid + 512 * k2) * 8];
        }

        if (valid) {
            f32x4 a00 = {0,0,0,0}, a01 = {0,0,0,0}, a10 = {0,0,0,0}, a11 = {0,0,0,0};
#pragma unroll
            for (int kb = 0; kb < 8; ++kb) {
                bf16x8 b0 = *(const bf16x8*)&bbuf[boff0 + kb * 512];
                bf16x8 b1 = *(const bf16x8*)&bbuf[boff1 + kb * 512];
                a00 = __builtin_amdgcn_mfma_f32_16x16x32_bf16(afrag[0][kb], b0, a00, 0, 0, 0);
                a10 = __builtin_amdgcn_mfma_f32_16x16x32_bf16(afrag[1][kb], b0, a10, 0, 0, 0);
                a01 = __builtin_amdgcn_mfma_f32_16x16x32_bf16(afrag[0][kb], b1, a01, 0, 0, 0);
                a11 = __builtin_amdgcn_mfma_f32_16x16x32_bf16(afrag[1][kb], b1, a11, 0, 0, 0);
            }
            float* sp = soutf + yy * SO_SZ;
#pragma unroll
            for (int mm = 0; mm < 2; ++mm)
#pragma unroll
            for (int nn = 0; nn < 2; ++nn)
#pragma unroll
            for (int r2 = 0; r2 < 4; ++r2) {
                const int xh  = 16 * mm + 4 * quad + r2;
                const int dxi = (16 * nn + m_lo) - xh + 10;
                const float vv = mm == 0 ? (nn == 0 ? a00[r2] : a01[r2])
                                         : (nn == 0 ? a10[r2] : a11[r2]);
                if ((unsigned)dxi <= 20u)
                    sp[dxi * SO_LD + 2 * xh + par] = vv;
            }
        }
        __asm__ __volatile__("s_waitcnt lgkmcnt(0)\n\ts_barrier" ::: "memory");

        if (more) {
#pragma unroll
            for (int k2 = 0; k2 < 4; ++k2)
                *(bf16x8*)&bbuf[(tid + 512 * k2) * 8] = Bst[k2];
        }
        if (valid) {
            const float* sp = soutf + yy * SO_SZ;
            float* ob = outyy + (size_t)dyi * ND * HW;
#pragma unroll
            for (int i = 0; i < 11; ++i) {
                const int e = i * 128 + t2;
                if (e < ND * NW)
                    __builtin_nontemporal_store(sp[(e >> 6) * SO_LD + (e & 63)] * scale,
                                                &ob[(size_t)(e >> 6) * HW + (e & 63)]);
            }
        }
        __asm__ __volatile__("s_waitcnt lgkmcnt(0)\n\ts_barrier" ::: "memory");
    }
}

// ---------- fallback (round-1 style) if ws is too small ----------------------
__global__ void __launch_bounds__(256, 2)
corr_fallback(const float* __restrict__ in1, const float* __restrict__ in2,
              float* __restrict__ out) {
    __shared__ unsigned short s1[ROW_ELEMS];
    __shared__ unsigned short s2[ROW_ELEMS];
    const int tid = threadIdx.x;
    const int b = blockIdx.x / NH, y = blockIdx.x % NH;
    const int lane = tid & 63, wave = tid >> 6;
    const int m_lo = lane & 15, quad = lane >> 4;
    const int asub = wave >> 1, bsub = wave & 1;
    {
        const int x = tid & 63, g0 = tid >> 6;
        const float* p = in1 + ((size_t)b * NC * NH + y) * NW + x;
        for (int i = 0; i < 8; ++i) {
            const int chunk = g0 * 8 + i;
            bf16x8 v = load_pack8(p, chunk * 8);
            *(bf16x8*)&s1[sw_addr(x, chunk)] = v;
        }
    }
    __syncthreads();
    bf16x8 afrag[2][8];
    for (int mm = 0; mm < 2; ++mm) {
        const int x = 32 * asub + 16 * mm + m_lo;
        for (int kb = 0; kb < 8; ++kb)
            afrag[mm][kb] = *(const bf16x8*)&s1[sw_addr(x, 4 * kb + quad)];
    }
    const float scale = 1.0f / 256.0f;
    for (int dyi = 0; dyi < ND; ++dyi) {
        const int ys = y + 2 * dyi - 20;
        float* ob = out + (((size_t)b * (ND * ND) + (size_t)dyi * ND) * NH + y) * NW;
        if ((unsigned)ys >= (unsigned)NH) {
            for (int i = tid; i < ND * NW; i += 256)
                ob[(size_t)(i >> 6) * HW + (i & 63)] = 0.0f;
            continue;
        }
        __syncthreads();
        {
            const int x = tid & 63, g0 = tid >> 6;
            const float* p = in2 + ((size_t)b * NC * NH + ys) * NW + x;
            for (int i = 0; i < 8; ++i) {
                const int chunk = g0 * 8 + i;
                bf16x8 v = load_pack8(p, chunk * 8);
                *(bf16x8*)&s2[sw_addr(x, chunk)] = v;
            }
        }
        __syncthreads();
        f32x4 acc[2][2];
        for (int mm = 0; mm < 2; ++mm)
            for (int nn = 0; nn < 2; ++nn) acc[mm][nn] = (f32x4){0.f, 0.f, 0.f, 0.f};
        for (int nn = 0; nn < 2; ++nn) {
            const int xpp = 32 * bsub + 16 * nn + m_lo;
            for (int kb = 0; kb < 8; ++kb) {
                bf16x8 bfrag = *(const bf16x8*)&s2[sw_addr(xpp, 4 * kb + quad)];
                acc[0][nn] = __builtin_amdgcn_mfma_f32_16x16x32_bf16(afrag[0][kb], bfrag, acc[0][nn], 0, 0, 0);
                acc[1][nn] = __builtin_amdgcn_mfma_f32_16x16x32_bf16(afrag[1][kb], bfrag, acc[1][nn], 0, 0, 0);
            }
        }
        for (int mm = 0; mm < 2; ++mm)
            for (int nn = 0; nn < 2; ++nn) {
                const int xb = 32 * asub + 16 * mm + 4 * quad;
                const int xpp = 32 * bsub + 16 * nn + m_lo;
                for (int r = 0; r < 4; ++r) {
                    const int x = xb + r, d = xpp - x;
                    if (d >= -20 && d <= 20 && !(d & 1))
                        ob[(size_t)((d + 20) >> 1) * HW + x] = acc[mm][nn][r] * scale;
                }
            }
        for (int i = tid; i < ND * 20; i += 256) {
            const int dxi = i / 20, j = i - dxi * 20;
            const int dx = 2 * dxi - 20, a = dx < 0 ? -dx : dx;
            if (j < a) {
                const int x = dx < 0 ? j : (NW - dx + j);
                ob[(size_t)dxi * HW + x] = 0.0f;
            }
        }
    }
}

extern "C" void kernel_launch(void* const* d_in, const int* in_sizes, int n_in,
                              void* d_out, int out_size, void* d_ws, size_t ws_size,
                              hipStream_t stream) {
    const float* in1 = (const float*)d_in[0];
    const float* in2 = (const float*)d_in[1];
    float* out = (float*)d_out;
    const size_t need = (size_t)NB * NH * ROW_ELEMS * sizeof(unsigned short);
    if (ws_size >= need) {
        convert_in2<<<dim3(NWG), dim3(256), 0, stream>>>(in2, (unsigned short*)d_ws);
        corr_main<<<dim3(576), dim3(512), 0, stream>>>(in1, (const unsigned short*)d_ws, out);
    } else {
        corr_fallback<<<dim3(NWG), dim3(256), 0, stream>>>(in1, in2, out);
    }
}

// Round 19
// 75.947 us; speedup vs baseline: 1.5400x; 1.5400x over previous
//
#include <hip/hip_runtime.h>
#include <stdint.h>

#define NB 16
#define NC 256
#define NH 48
#define NW 64
#define ND 21
#define HW (NH * NW)
#define ROW_ELEMS (NW * NC)   // one (b,y) row: 16384 bf16 = 32KB
#define NXCD 8
#define NWG (NB * NH)         // 768 (convert grid)
#define SO_LD 65              // padded plane leading dim (scatter <=4-way)
#define SO_SZ (ND * SO_LD)    // 1365 floats per plane

typedef __bf16 bf16x8 __attribute__((ext_vector_type(8)));
typedef float f32x4 __attribute__((ext_vector_type(4)));

// direct global->LDS DMA, 16B per lane; LDS dest = uniform base + lane*16
#define GLOAD_LDS16(g, l) __builtin_amdgcn_global_load_lds(               \
    (const __attribute__((address_space(1))) unsigned int*)(g),           \
    (__attribute__((address_space(3))) unsigned int*)(l), 16, 0, 0)

// convert grid (768): XCD k owns wg [k*96, k*96+96) = batches {2k,2k+1}
__device__ __forceinline__ int xcd_wg(int orig) {
    return (orig & (NXCD - 1)) * (NWG / NXCD) + (orig >> 3);
}

// full-row LDS layout [pos][c] bf16, XOR-swizzled 16B chunks (conflict-free b128)
__device__ __forceinline__ int sw_addr(int x, int chunk) {
    int cs = (chunk & ~7) | ((chunk ^ x) & 7);
    return x * 256 + (cs << 3);
}
// parity permutation: even x -> pos 0..31, odd x -> pos 32..63
__device__ __forceinline__ int posx(int x) { return ((x & 1) << 5) | (x >> 1); }

// ws (in2) GLOBAL fragment order: slice w=(nt<<1)|par, per-kb 1KB contiguous
__device__ __forceinline__ int frag_off(int w, int kb, int l) {
    return w * 4096 + kb * 512 + ((l ^ ((w & 3) << 1)) << 3);
}

__device__ __forceinline__ bf16x8 load_pack8(const float* __restrict__ p, int cbase) {
    bf16x8 v;
#pragma unroll
    for (int j = 0; j < 8; ++j)
        v[j] = (__bf16)p[(size_t)(cbase + j) * HW];
    return v;
}

// ---------- pre-pass: in2 fp32 [b][c][h][w] -> ws bf16 rows (fragment order) --
__global__ void __launch_bounds__(256, 4)
convert_in2(const float* __restrict__ in2, unsigned short* __restrict__ ws) {
    __shared__ unsigned short s[ROW_ELEMS];
    const int tid = threadIdx.x;
    const int wg = xcd_wg(blockIdx.x);
    const int b = wg / NH, y = wg % NH;
    const int x = tid & 63, g0 = tid >> 6;
    const int par = x & 1, m_lo = (x >> 1) & 15, nt = x >> 5;
    const int w = (nt << 1) | par;
    const float* p = in2 + ((size_t)b * NC * NH + y) * NW + x;
#pragma unroll
    for (int i = 0; i < 8; ++i) {
        const int chunk = g0 * 8 + i;
        const int kb = chunk >> 2, quad = chunk & 3;
        const int l = (quad << 4) | m_lo;
        bf16x8 v = load_pack8(p, chunk * 8);
        *(bf16x8*)&s[frag_off(w, kb, l)] = v;
    }
    __syncthreads();
    unsigned short* wr = ws + ((size_t)b * NH + y) * ROW_ELEMS;
#pragma unroll
    for (int i = 0; i < 8; ++i) {
        const int e = (i * 256 + tid) * 8;
        *(bf16x8*)(wr + e) = *(const bf16x8*)(s + e);
    }
}

// ---------- main: block = (b, P, 4-y group, ys-third); 576 blocks x 512 -----
// Co-residency without spills: B staged by global_load_lds DMA (no Bst regs),
// 54.6KB LDS -> two independent blocks/CU. BUGFIX vs R18: waves with
// valid==false issued DMAs but no stores — vmcnt(8) didn't cover their DMAs
// (race -> absmax 0.102). Now: store-issuing waves use vmcnt(8); DMA-only
// waves use vmcnt(0).
__global__ void __launch_bounds__(512, 4)
corr_main(const float* __restrict__ in1, const unsigned short* __restrict__ ws,
          float* __restrict__ out) {
    // [0,32768): bbuf (B row; also prologue in1 staging)
    // [32768,54608): 4 sout planes [ND][SO_LD]
    __shared__ __align__(16) unsigned char smem[54608];
    unsigned short* bbuf  = (unsigned short*)smem;
    float*          soutf = (float*)(smem + 32768);

    const int tid = threadIdx.x;
    const int bid = blockIdx.x;
    const int xcd = bid & 7;                  // all blocks of b on one XCD
    const int r   = bid >> 3;                 // 0..71
    const int b   = 2 * xcd + (r >= 36 ? 1 : 0);
    const int v   = r - (r >= 36 ? 36 : 0);   // 0..35
    const int P   = v & 1;
    const int w2  = v >> 1;                   // 0..17
    const int g   = w2 % 6, ti = w2 / 6;      // y-group, ys-third
    const int y0  = 8 * g + P;

    const int lane = tid & 63, wave = tid >> 6;   // 8 waves
    const int m_lo = lane & 15, quad = lane >> 4;
    const int par  = wave & 1, yy = wave >> 1;    // wave = (par, yy in 0..3)
    const int y    = y0 + 2 * yy;                 // this wave's output row

    const int lo = max(y0 - 20, P);
    const int hi = min(y0 + 26, 46 + P);
    const int n  = ((hi - lo) >> 1) + 1;          // 14..22
    const int q  = (n + 2) / 3;                   // 5..8
    const int lo_t = lo + 2 * q * ti;
    const int nh   = min(q, n - q * ti);          // >= 4 always

    const unsigned short* wsb = ws + (size_t)b * NH * ROW_ELEMS;

    // ---- prologue: 4 rounds; stage in1 row y0+2*rnd into bbuf; wave-pair
    // yy==rnd extracts its A fragments (A stays in registers all kernel)
    bf16x8 afrag[2][8];
#pragma unroll 1
    for (int rnd = 0; rnd < 4; ++rnd) {
        const float* pr = in1 + ((size_t)b * NC * NH + (y0 + 2 * rnd)) * NW;
#pragma unroll
        for (int i = 0; i < 4; ++i) {
            const int pk = i * 512 + tid;          // 2048 packs per row
            const int x = pk & 63, ch = pk >> 6;
            bf16x8 vv = load_pack8(pr + x, ch * 8);
            *(bf16x8*)&bbuf[sw_addr(posx(x), ch)] = vv;
        }
        __asm__ __volatile__("s_waitcnt lgkmcnt(0)\n\ts_barrier" ::: "memory");
        if (yy == rnd) {
            const int pos0 = par * 32 + m_lo;
#pragma unroll
            for (int kb = 0; kb < 8; ++kb) {
                afrag[0][kb] = *(const bf16x8*)&bbuf[sw_addr(pos0,      4 * kb + quad)];
                afrag[1][kb] = *(const bf16x8*)&bbuf[sw_addr(pos0 + 16, 4 * kb + quad)];
            }
        }
        __asm__ __volatile__("s_waitcnt lgkmcnt(0)\n\ts_barrier" ::: "memory");
    }

    // ---- first B row DMA into bbuf (4 chunks of 1KB per wave; 32 total)
    {
        const unsigned short* row = wsb + (size_t)lo_t * ROW_ELEMS;
        asm volatile("" ::: "memory");
#pragma unroll
        for (int i = 0; i < 4; ++i) {
            const int ch = wave * 4 + i;
            GLOAD_LDS16(row + ch * 512 + lane * 8, bbuf + ch * 512);
        }
        asm volatile("" ::: "memory");
    }

    // zero the 4 planes (band-invalid slots stay zero forever)
    for (int i = tid; i < 4 * SO_SZ; i += 512) soutf[i] = 0.0f;

    // zero out-of-range dy planes (only the ti==0 block of each group)
    float* outyy = out + (size_t)b * (ND * ND) * HW + (size_t)y * NW;
    const int d0 = (y >= 20) ? 0 : ((21 - y) >> 1);
    const int d1 = min(20, (67 - y) >> 1);
    const int t2 = par * 64 + lane;               // 0..127 in wave-pair
    if (ti == 0) {
        for (int z = 0; z < ND; ++z) {
            if (z >= d0 && z <= d1) continue;
            float* ob = outyy + (size_t)z * ND * HW;
#pragma unroll
            for (int i = 0; i < 11; ++i) {
                const int e = i * 128 + t2;
                if (e < ND * NW)
                    __builtin_nontemporal_store(0.0f, &ob[(size_t)(e >> 6) * HW + (e & 63)]);
            }
        }
    }
    // publish first B row (one-time full drain: DMA + zeroing stores)
    asm volatile("s_waitcnt vmcnt(0) lgkmcnt(0)\n\ts_barrier" ::: "memory");

    const float scale = 1.0f / 256.0f;
    const int boff0 = frag_off((0 << 1) | par, 0, lane);
    const int boff1 = frag_off((1 << 1) | par, 0, lane);
    const int D0 = ((lo_t - y) >> 1) + 10;        // dyi at k=0

    // step (2 phases):
    //  A: 32 MFMA from bbuf; scatter plane yy. bar(lgkm) — all bbuf ds-reads
    //     and scatter writes complete before B's DMA overwrites bbuf.
    //  B: DMA row k+1 -> bbuf; drain plane yy -> global nt.
    //     end wait (per wave-uniform case):
    //       stores issued (valid): vmcnt(8) — >=10 stores are newer than the
    //         4 DMAs, so <=8 outstanding proves DMAs retired; stores fly on.
    //       DMA only (!valid):     vmcnt(0) — must drain own DMAs (rare wave).
    //       last step:             lgkm only (no DMA issued).
    for (int k = 0; k < nh; ++k) {
        const int dyi = D0 + k;
        const bool valid = (unsigned)dyi <= 20u;   // wave-uniform
        const bool more = (k + 1 < nh);

        if (valid) {
            f32x4 a00 = {0,0,0,0}, a01 = {0,0,0,0}, a10 = {0,0,0,0}, a11 = {0,0,0,0};
#pragma unroll
            for (int kb = 0; kb < 8; ++kb) {
                bf16x8 b0 = *(const bf16x8*)&bbuf[boff0 + kb * 512];
                bf16x8 b1 = *(const bf16x8*)&bbuf[boff1 + kb * 512];
                a00 = __builtin_amdgcn_mfma_f32_16x16x32_bf16(afrag[0][kb], b0, a00, 0, 0, 0);
                a10 = __builtin_amdgcn_mfma_f32_16x16x32_bf16(afrag[1][kb], b0, a10, 0, 0, 0);
                a01 = __builtin_amdgcn_mfma_f32_16x16x32_bf16(afrag[0][kb], b1, a01, 0, 0, 0);
                a11 = __builtin_amdgcn_mfma_f32_16x16x32_bf16(afrag[1][kb], b1, a11, 0, 0, 0);
            }
            float* sp = soutf + yy * SO_SZ;
#pragma unroll
            for (int mm = 0; mm < 2; ++mm)
#pragma unroll
            for (int nn = 0; nn < 2; ++nn)
#pragma unroll
            for (int r2 = 0; r2 < 4; ++r2) {
                const int xh  = 16 * mm + 4 * quad + r2;
                const int dxi = (16 * nn + m_lo) - xh + 10;
                const float vv = mm == 0 ? (nn == 0 ? a00[r2] : a01[r2])
                                         : (nn == 0 ? a10[r2] : a11[r2]);
                if ((unsigned)dxi <= 20u)
                    sp[dxi * SO_LD + 2 * xh + par] = vv;
            }
        }
        __asm__ __volatile__("s_waitcnt lgkmcnt(0)\n\ts_barrier" ::: "memory");

        if (more) {
            const unsigned short* row = wsb + (size_t)(lo_t + 2 * (k + 1)) * ROW_ELEMS;
            asm volatile("" ::: "memory");
#pragma unroll
            for (int i = 0; i < 4; ++i) {
                const int ch = wave * 4 + i;
                GLOAD_LDS16(row + ch * 512 + lane * 8, bbuf + ch * 512);
            }
            asm volatile("" ::: "memory");
        }
        if (valid) {
            const float* sp = soutf + yy * SO_SZ;
            float* ob = outyy + (size_t)dyi * ND * HW;
#pragma unroll
            for (int i = 0; i < 11; ++i) {
                const int e = i * 128 + t2;
                if (e < ND * NW)
                    __builtin_nontemporal_store(sp[(e >> 6) * SO_LD + (e & 63)] * scale,
                                                &ob[(size_t)(e >> 6) * HW + (e & 63)]);
            }
        }
        if (more) {
            if (valid)
                asm volatile("s_waitcnt lgkmcnt(0) vmcnt(8)\n\ts_barrier" ::: "memory");
            else
                asm volatile("s_waitcnt lgkmcnt(0) vmcnt(0)\n\ts_barrier" ::: "memory");
        } else {
            asm volatile("s_waitcnt lgkmcnt(0)\n\ts_barrier" ::: "memory");
        }
    }
}

// ---------- fallback (round-1 style) if ws is too small ----------------------
__global__ void __launch_bounds__(256, 2)
corr_fallback(const float* __restrict__ in1, const float* __restrict__ in2,
              float* __restrict__ out) {
    __shared__ unsigned short s1[ROW_ELEMS];
    __shared__ unsigned short s2[ROW_ELEMS];
    const int tid = threadIdx.x;
    const int b = blockIdx.x / NH, y = blockIdx.x % NH;
    const int lane = tid & 63, wave = tid >> 6;
    const int m_lo = lane & 15, quad = lane >> 4;
    const int asub = wave >> 1, bsub = wave & 1;
    {
        const int x = tid & 63, g0 = tid >> 6;
        const float* p = in1 + ((size_t)b * NC * NH + y) * NW + x;
        for (int i = 0; i < 8; ++i) {
            const int chunk = g0 * 8 + i;
            bf16x8 v = load_pack8(p, chunk * 8);
            *(bf16x8*)&s1[sw_addr(x, chunk)] = v;
        }
    }
    __syncthreads();
    bf16x8 afrag[2][8];
    for (int mm = 0; mm < 2; ++mm) {
        const int x = 32 * asub + 16 * mm + m_lo;
        for (int kb = 0; kb < 8; ++kb)
            afrag[mm][kb] = *(const bf16x8*)&s1[sw_addr(x, 4 * kb + quad)];
    }
    const float scale = 1.0f / 256.0f;
    for (int dyi = 0; dyi < ND; ++dyi) {
        const int ys = y + 2 * dyi - 20;
        float* ob = out + (((size_t)b * (ND * ND) + (size_t)dyi * ND) * NH + y) * NW;
        if ((unsigned)ys >= (unsigned)NH) {
            for (int i = tid; i < ND * NW; i += 256)
                ob[(size_t)(i >> 6) * HW + (i & 63)] = 0.0f;
            continue;
        }
        __syncthreads();
        {
            const int x = tid & 63, g0 = tid >> 6;
            const float* p = in2 + ((size_t)b * NC * NH + ys) * NW + x;
            for (int i = 0; i < 8; ++i) {
                const int chunk = g0 * 8 + i;
                bf16x8 v = load_pack8(p, chunk * 8);
                *(bf16x8*)&s2[sw_addr(x, chunk)] = v;
            }
        }
        __syncthreads();
        f32x4 acc[2][2];
        for (int mm = 0; mm < 2; ++mm)
            for (int nn = 0; nn < 2; ++nn) acc[mm][nn] = (f32x4){0.f, 0.f, 0.f, 0.f};
        for (int nn = 0; nn < 2; ++nn) {
            const int xpp = 32 * bsub + 16 * nn + m_lo;
            for (int kb = 0; kb < 8; ++kb) {
                bf16x8 bfrag = *(const bf16x8*)&s2[sw_addr(xpp, 4 * kb + quad)];
                acc[0][nn] = __builtin_amdgcn_mfma_f32_16x16x32_bf16(afrag[0][kb], bfrag, acc[0][nn], 0, 0, 0);
                acc[1][nn] = __builtin_amdgcn_mfma_f32_16x16x32_bf16(afrag[1][kb], bfrag, acc[1][nn], 0, 0, 0);
            }
        }
        for (int mm = 0; mm < 2; ++mm)
            for (int nn = 0; nn < 2; ++nn) {
                const int xb = 32 * asub + 16 * mm + 4 * quad;
                const int xpp = 32 * bsub + 16 * nn + m_lo;
                for (int r = 0; r < 4; ++r) {
                    const int x = xb + r, d = xpp - x;
                    if (d >= -20 && d <= 20 && !(d & 1))
                        ob[(size_t)((d + 20) >> 1) * HW + x] = acc[mm][nn][r] * scale;
                }
            }
        for (int i = tid; i < ND * 20; i += 256) {
            const int dxi = i / 20, j = i - dxi * 20;
            const int dx = 2 * dxi - 20, a = dx < 0 ? -dx : dx;
            if (j < a) {
                const int x = dx < 0 ? j : (NW - dx + j);
                ob[(size_t)dxi * HW + x] = 0.0f;
            }
        }
    }
}

extern "C" void kernel_launch(void* const* d_in, const int* in_sizes, int n_in,
                              void* d_out, int out_size, void* d_ws, size_t ws_size,
                              hipStream_t stream) {
    const float* in1 = (const float*)d_in[0];
    const float* in2 = (const float*)d_in[1];
    float* out = (float*)d_out;
    const size_t need = (size_t)NB * NH * ROW_ELEMS * sizeof(unsigned short);
    if (ws_size >= need) {
        convert_in2<<<dim3(NWG), dim3(256), 0, stream>>>(in2, (unsigned short*)d_ws);
        corr_main<<<dim3(576), dim3(512), 0, stream>>>(in1, (const unsigned short*)d_ws, out);
    } else {
        corr_fallback<<<dim3(NWG), dim3(256), 0, stream>>>(in1, in2, out);
    }
}

// Round 20
// 47.421 us; speedup vs baseline: 2.4664x; 1.6015x over previous
//
#include <hip/hip_runtime.h>
#include <stdint.h>

#define NB 16
#define NC 256
#define NH 48
#define NW 64
#define ND 21
#define HW (NH * NW)
#define ROW_ELEMS (NW * NC)   // one (b,y) row: 16384 bf16 = 32KB
#define NXCD 8
#define NWG (NB * NH)         // 768 (convert grid)
#define SO_LD 65              // padded plane leading dim (scatter <=4-way)
#define SO_SZ (ND * SO_LD)    // 1365 floats per plane

typedef __bf16 bf16x8 __attribute__((ext_vector_type(8)));
typedef float f32x4 __attribute__((ext_vector_type(4)));

// direct global->LDS DMA, 16B per lane; LDS dest = uniform base + lane*16
#define GLOAD_LDS16(g, l) __builtin_amdgcn_global_load_lds(               \
    (const __attribute__((address_space(1))) unsigned int*)(g),           \
    (__attribute__((address_space(3))) unsigned int*)(l), 16, 0, 0)

// convert grid (768): XCD k owns wg [k*96, k*96+96) = batches {2k,2k+1}
__device__ __forceinline__ int xcd_wg(int orig) {
    return (orig & (NXCD - 1)) * (NWG / NXCD) + (orig >> 3);
}

// full-row LDS layout [pos][c] bf16, XOR-swizzled 16B chunks (conflict-free b128)
__device__ __forceinline__ int sw_addr(int x, int chunk) {
    int cs = (chunk & ~7) | ((chunk ^ x) & 7);
    return x * 256 + (cs << 3);
}
// parity permutation: even x -> pos 0..31, odd x -> pos 32..63
__device__ __forceinline__ int posx(int x) { return ((x & 1) << 5) | (x >> 1); }

// ws (in2) GLOBAL fragment order: slice w=(nt<<1)|par, per-kb 1KB contiguous
__device__ __forceinline__ int frag_off(int w, int kb, int l) {
    return w * 4096 + kb * 512 + ((l ^ ((w & 3) << 1)) << 3);
}

__device__ __forceinline__ bf16x8 load_pack8(const float* __restrict__ p, int cbase) {
    bf16x8 v;
#pragma unroll
    for (int j = 0; j < 8; ++j)
        v[j] = (__bf16)p[(size_t)(cbase + j) * HW];
    return v;
}

// ---------- pre-pass: in2 fp32 [b][c][h][w] -> ws bf16 rows (fragment order) --
__global__ void __launch_bounds__(256, 4)
convert_in2(const float* __restrict__ in2, unsigned short* __restrict__ ws) {
    __shared__ unsigned short s[ROW_ELEMS];
    const int tid = threadIdx.x;
    const int wg = xcd_wg(blockIdx.x);
    const int b = wg / NH, y = wg % NH;
    const int x = tid & 63, g0 = tid >> 6;
    const int par = x & 1, m_lo = (x >> 1) & 15, nt = x >> 5;
    const int w = (nt << 1) | par;
    const float* p = in2 + ((size_t)b * NC * NH + y) * NW + x;
#pragma unroll
    for (int i = 0; i < 8; ++i) {
        const int chunk = g0 * 8 + i;
        const int kb = chunk >> 2, quad = chunk & 3;
        const int l = (quad << 4) | m_lo;
        bf16x8 v = load_pack8(p, chunk * 8);
        *(bf16x8*)&s[frag_off(w, kb, l)] = v;
    }
    __syncthreads();
    unsigned short* wr = ws + ((size_t)b * NH + y) * ROW_ELEMS;
#pragma unroll
    for (int i = 0; i < 8; ++i) {
        const int e = (i * 256 + tid) * 8;
        *(bf16x8*)(wr + e) = *(const bf16x8*)(s + e);
    }
}

// ---------- main: block = (b, P, 6-y group, ys-half); 256 blocks x 768 ------
// R7 structure + global_load_lds B staging (double-buffered) + counted vmcnt:
// output nt-stores are never drained in the loop. Session-best configuration
// (R9: 49.1 us harness / 55.1 us main) — restored after the co-residency
// experiment (R19: 2 blocks/CU achieved, Occ 33%, but 87 us) falsified the
// occupancy axis. Floor here is per-CU B-byte volume x phase-locked pipe-sum;
// 6-y reuse minimizes it among all 11 structures tested.
__global__ void __launch_bounds__(768, 1)
corr_main(const float* __restrict__ in1, const unsigned short* __restrict__ ws,
          float* __restrict__ out) {
    // [0,65536): bbuf double buffer (2 x 32KB ws rows, fragment layout)
    // [65536,131072): 12 sout planes [ND][SO_LD] (two sets of 6)
    // prologue overlays [65536,131072) as two in1-row staging regions
    __shared__ __align__(16) unsigned char smem[131072];
    unsigned short* bbuf  = (unsigned short*)smem;
    float*          soutf = (float*)(smem + 65536);
    unsigned short* reg0  = (unsigned short*)(smem + 65536);
    unsigned short* reg1  = (unsigned short*)(smem + 98304);

    const int tid = threadIdx.x;
    const int bid = blockIdx.x;
    const int xcd = bid & 7;                   // all blocks of b on one XCD
    const int u   = bid >> 3;                  // 0..31
    const int b   = 2 * xcd + (u >> 4);
    const int v   = u & 15;
    const int P   = v & 1, g = (v >> 1) & 3, half = v >> 3;
    const int y0  = 12 * g + P;
    const int lane = tid & 63, wave = tid >> 6;   // 12 waves
    const int m_lo = lane & 15, quad = lane >> 4;
    const int par  = wave & 1, yy = wave >> 1;    // wave = (par, yy)
    const int y    = y0 + 2 * yy;                 // this wave's output row

    const int lo = max(y0 - 20, P);
    const int hi = min(y0 + 30, 46 + P);
    const int n  = ((hi - lo) >> 1) + 1;          // 16..22
    const int n0 = (n + 1) >> 1;
    const int lo_h = half ? (lo + 2 * n0) : lo;
    const int nh   = half ? (n - n0) : n0;        // >= 8 always

    const unsigned short* wsb = ws + (size_t)b * NH * ROW_ELEMS;
    const bool loader = (wave < 8);               // waves 0-7 DMA B rows

    // issue first B row DMA immediately (lands under the in1 prologue)
    if (loader) {
        const unsigned short* row = wsb + (size_t)lo_h * ROW_ELEMS;
        asm volatile("" ::: "memory");
#pragma unroll
        for (int i = 0; i < 4; ++i) {
            const int ch = wave * 4 + i;          // 32 chunks x 1KB = 32KB
            GLOAD_LDS16(row + ch * 512 + lane * 8, bbuf + ch * 512);
        }
        asm volatile("" ::: "memory");
    }

    // ---- prologue: stage 6 in1 rows (2 per round), wave (yy>>1)==rnd extracts
    bf16x8 afrag[2][8];
#pragma unroll 1
    for (int rnd = 0; rnd < 3; ++rnd) {
        const int yA = y0 + 4 * rnd;              // rows yA, yA+2
#pragma unroll
        for (int i = 0; i < 6; ++i) {
            const int uu = i * 768 + tid;
            if (uu < 4096) {
                const int row = uu >> 11, cu = uu & 2047;
                const int x = cu & 63, chunk = cu >> 6;
                const float* p = in1 + ((size_t)b * NC * NH + (yA + 2 * row)) * NW + x;
                bf16x8 vv = load_pack8(p, chunk * 8);
                unsigned short* dst = row ? reg1 : reg0;
                *(bf16x8*)&dst[sw_addr(posx(x), chunk)] = vv;
            }
        }
        __asm__ __volatile__("s_waitcnt lgkmcnt(0)\n\ts_barrier" ::: "memory");
        if ((yy >> 1) == rnd) {
            const unsigned short* src = (yy & 1) ? reg1 : reg0;
            const int pos0 = par * 32 + m_lo;
#pragma unroll
            for (int kb = 0; kb < 8; ++kb) {
                afrag[0][kb] = *(const bf16x8*)&src[sw_addr(pos0,      4 * kb + quad)];
                afrag[1][kb] = *(const bf16x8*)&src[sw_addr(pos0 + 16, 4 * kb + quad)];
            }
        }
        __asm__ __volatile__("s_waitcnt lgkmcnt(0)\n\ts_barrier" ::: "memory");
    }

    // zero both sout plane sets (band-invalid slots stay zero forever)
    for (int i = tid; i < 12 * SO_SZ; i += 768) soutf[i] = 0.0f;

    // zero this half's out-of-range dy planes (per wave-pair, nontemporal)
    float* outyy = out + (size_t)b * (ND * ND) * HW + (size_t)y * NW;
    const int d0 = (y >= 20) ? 0 : ((21 - y) >> 1);
    const int d1 = min(20, (67 - y) >> 1);
    const int zlo = half ? (d1 + 1) : 0;
    const int zhi = half ? ND : d0;
    const int t2  = par * 64 + lane;              // 0..127 in wave-pair
    for (int z = zlo; z < zhi; ++z) {
        float* ob = outyy + (size_t)z * ND * HW;
#pragma unroll
        for (int i = 0; i < 11; ++i) {
            const int e = i * 128 + t2;
            if (e < ND * NW)
                __builtin_nontemporal_store(0.0f, &ob[(size_t)(e >> 6) * HW + (e & 63)]);
        }
    }
    // loaders confirm first B row landed; publish to all waves
    if (loader) asm volatile("s_waitcnt vmcnt(0)" ::: "memory");
    __asm__ __volatile__("s_waitcnt lgkmcnt(0)\n\ts_barrier" ::: "memory");

    const float scale = 1.0f / 256.0f;
    const int boff0 = frag_off((0 << 1) | par, 0, lane);
    const int boff1 = frag_off((1 << 1) | par, 0, lane);

    // one step, ONE barrier: DMA next row into bbuf[cur^1]; MFMA from
    // bbuf[cur]; scatter into sout set cur; drain set cur^1 (prev step) to
    // global nt. End: lgkmcnt(0) + counted vmcnt (drains DMA loads only,
    // leaves the 11 output stores in flight) + s_barrier.
    for (int k = 0; k < nh; ++k) {
        const int ys = lo_h + 2 * k;
        const int cur = k & 1;
        const unsigned short* bb = bbuf + cur * 16384;

        if (k + 1 < nh && loader) {
            const unsigned short* row = wsb + (size_t)(ys + 2) * ROW_ELEMS;
            unsigned short* dstb = bbuf + (cur ^ 1) * 16384;
            asm volatile("" ::: "memory");
#pragma unroll
            for (int i = 0; i < 4; ++i) {
                const int ch = wave * 4 + i;
                GLOAD_LDS16(row + ch * 512 + lane * 8, dstb + ch * 512);
            }
            asm volatile("" ::: "memory");
        }

        const int dyi = ((ys - y) >> 1) + 10;
        const bool valid = (unsigned)dyi <= 20u;   // wave-uniform

        if (valid) {
            f32x4 a00 = {0,0,0,0}, a01 = {0,0,0,0}, a10 = {0,0,0,0}, a11 = {0,0,0,0};
#pragma unroll
            for (int kb = 0; kb < 8; ++kb) {
                bf16x8 b0 = *(const bf16x8*)&bb[boff0 + kb * 512];
                bf16x8 b1 = *(const bf16x8*)&bb[boff1 + kb * 512];
                a00 = __builtin_amdgcn_mfma_f32_16x16x32_bf16(afrag[0][kb], b0, a00, 0, 0, 0);
                a10 = __builtin_amdgcn_mfma_f32_16x16x32_bf16(afrag[1][kb], b0, a10, 0, 0, 0);
                a01 = __builtin_amdgcn_mfma_f32_16x16x32_bf16(afrag[0][kb], b1, a01, 0, 0, 0);
                a11 = __builtin_amdgcn_mfma_f32_16x16x32_bf16(afrag[1][kb], b1, a11, 0, 0, 0);
            }
            float* sp = soutf + (cur * 6 + yy) * SO_SZ;
#pragma unroll
            for (int mm = 0; mm < 2; ++mm)
#pragma unroll
            for (int nn = 0; nn < 2; ++nn)
#pragma unroll
            for (int r = 0; r < 4; ++r) {
                const int xh  = 16 * mm + 4 * quad + r;
                const int dxi = (16 * nn + m_lo) - xh + 10;
                const float vv = mm == 0 ? (nn == 0 ? a00[r] : a01[r])
                                         : (nn == 0 ? a10[r] : a11[r]);
                if ((unsigned)dxi <= 20u)
                    sp[dxi * SO_LD + 2 * xh + par] = vv;
            }
        }

        // drain previous step's plane from the other set
        const int dyp = dyi - 1;
        const bool drain = (k > 0) && ((unsigned)dyp <= 20u);
        if (drain) {
            const float* sp = soutf + ((cur ^ 1) * 6 + yy) * SO_SZ;
            float* ob = outyy + (size_t)dyp * ND * HW;
#pragma unroll
            for (int i = 0; i < 11; ++i) {
                const int e = i * 128 + t2;
                if (e < ND * NW)
                    __builtin_nontemporal_store(sp[(e >> 6) * SO_LD + (e & 63)] * scale,
                                                &ob[(size_t)(e >> 6) * HW + (e & 63)]);
            }
        }
        // counted wait: 11 stores (just issued) stay in flight; DMA loads drain
        if (drain)
            asm volatile("s_waitcnt lgkmcnt(0) vmcnt(11)\n\ts_barrier" ::: "memory");
        else
            asm volatile("s_waitcnt lgkmcnt(0) vmcnt(0)\n\ts_barrier" ::: "memory");
    }

    // epilogue: drain the final step's plane (visibility via last barrier)
    {
        const int ysL = lo_h + 2 * (nh - 1);
        const int dyL = ((ysL - y) >> 1) + 10;
        if ((unsigned)dyL <= 20u) {
            const float* sp = soutf + (((nh - 1) & 1) * 6 + yy) * SO_SZ;
            float* ob = outyy + (size_t)dyL * ND * HW;
#pragma unroll
            for (int i = 0; i < 11; ++i) {
                const int e = i * 128 + t2;
                if (e < ND * NW)
                    __builtin_nontemporal_store(sp[(e >> 6) * SO_LD + (e & 63)] * scale,
                                                &ob[(size_t)(e >> 6) * HW + (e & 63)]);
            }
        }
    }
}

// ---------- fallback (round-1 style) if ws is too small ----------------------
__global__ void __launch_bounds__(256, 2)
corr_fallback(const float* __restrict__ in1, const float* __restrict__ in2,
              float* __restrict__ out) {
    __shared__ unsigned short s1[ROW_ELEMS];
    __shared__ unsigned short s2[ROW_ELEMS];
    const int tid = threadIdx.x;
    const int b = blockIdx.x / NH, y = blockIdx.x % NH;
    const int lane = tid & 63, wave = tid >> 6;
    const int m_lo = lane & 15, quad = lane >> 4;
    const int asub = wave >> 1, bsub = wave & 1;
    {
        const int x = tid & 63, g0 = tid >> 6;
        const float* p = in1 + ((size_t)b * NC * NH + y) * NW + x;
        for (int i = 0; i < 8; ++i) {
            const int chunk = g0 * 8 + i;
            bf16x8 v = load_pack8(p, chunk * 8);
            *(bf16x8*)&s1[sw_addr(x, chunk)] = v;
        }
    }
    __syncthreads();
    bf16x8 afrag[2][8];
    for (int mm = 0; mm < 2; ++mm) {
        const int x = 32 * asub + 16 * mm + m_lo;
        for (int kb = 0; kb < 8; ++kb)
            afrag[mm][kb] = *(const bf16x8*)&s1[sw_addr(x, 4 * kb + quad)];
    }
    const float scale = 1.0f / 256.0f;
    for (int dyi = 0; dyi < ND; ++dyi) {
        const int ys = y + 2 * dyi - 20;
        float* ob = out + (((size_t)b * (ND * ND) + (size_t)dyi * ND) * NH + y) * NW;
        if ((unsigned)ys >= (unsigned)NH) {
            for (int i = tid; i < ND * NW; i += 256)
                ob[(size_t)(i >> 6) * HW + (i & 63)] = 0.0f;
            continue;
        }
        __syncthreads();
        {
            const int x = tid & 63, g0 = tid >> 6;
            const float* p = in2 + ((size_t)b * NC * NH + ys) * NW + x;
            for (int i = 0; i < 8; ++i) {
                const int chunk = g0 * 8 + i;
                bf16x8 v = load_pack8(p, chunk * 8);
                *(bf16x8*)&s2[sw_addr(x, chunk)] = v;
            }
        }
        __syncthreads();
        f32x4 acc[2][2];
        for (int mm = 0; mm < 2; ++mm)
            for (int nn = 0; nn < 2; ++nn) acc[mm][nn] = (f32x4){0.f, 0.f, 0.f, 0.f};
        for (int nn = 0; nn < 2; ++nn) {
            const int xpp = 32 * bsub + 16 * nn + m_lo;
            for (int kb = 0; kb < 8; ++kb) {
                bf16x8 bfrag = *(const bf16x8*)&s2[sw_addr(xpp, 4 * kb + quad)];
                acc[0][nn] = __builtin_amdgcn_mfma_f32_16x16x32_bf16(afrag[0][kb], bfrag, acc[0][nn], 0, 0, 0);
                acc[1][nn] = __builtin_amdgcn_mfma_f32_16x16x32_bf16(afrag[1][kb], bfrag, acc[1][nn], 0, 0, 0);
            }
        }
        for (int mm = 0; mm < 2; ++mm)
            for (int nn = 0; nn < 2; ++nn) {
                const int xb = 32 * asub + 16 * mm + 4 * quad;
                const int xpp = 32 * bsub + 16 * nn + m_lo;
                for (int r = 0; r < 4; ++r) {
                    const int x = xb + r, d = xpp - x;
                    if (d >= -20 && d <= 20 && !(d & 1))
                        ob[(size_t)((d + 20) >> 1) * HW + x] = acc[mm][nn][r] * scale;
                }
            }
        for (int i = tid; i < ND * 20; i += 256) {
            const int dxi = i / 20, j = i - dxi * 20;
            const int dx = 2 * dxi - 20, a = dx < 0 ? -dx : dx;
            if (j < a) {
                const int x = dx < 0 ? j : (NW - dx + j);
                ob[(size_t)dxi * HW + x] = 0.0f;
            }
        }
    }
}

extern "C" void kernel_launch(void* const* d_in, const int* in_sizes, int n_in,
                              void* d_out, int out_size, void* d_ws, size_t ws_size,
                              hipStream_t stream) {
    const float* in1 = (const float*)d_in[0];
    const float* in2 = (const float*)d_in[1];
    float* out = (float*)d_out;
    const size_t need = (size_t)NB * NH * ROW_ELEMS * sizeof(unsigned short);
    if (ws_size >= need) {
        convert_in2<<<dim3(NWG), dim3(256), 0, stream>>>(in2, (unsigned short*)d_ws);
        corr_main<<<dim3(256), dim3(768), 0, stream>>>(in1, (const unsigned short*)d_ws, out);
    } else {
        corr_fallback<<<dim3(NWG), dim3(256), 0, stream>>>(in1, in2, out);
    }
}